// Round 5
// baseline (1232.994 us; speedup 1.0000x reference)
//
#include <hip/hip_runtime.h>
#include <stdint.h>

#define BB 64
#define TT 2048
#define KK 128
#define WSTRIDE 132   // words per W row: pad 128+4 -> lane k / chunk c hits
                      // bank-quad (k+c)%8: all 8 quads, structural-floor reads

typedef float f32x16 __attribute__((ext_vector_type(16)));
typedef float f32x2  __attribute__((ext_vector_type(2)));

__device__ __forceinline__ float waveMax(float v) {
#pragma unroll
    for (int off = 32; off; off >>= 1) v = fmaxf(v, __shfl_xor(v, off, 64));
    return v;
}
__device__ __forceinline__ float waveSum(float v) {
#pragma unroll
    for (int off = 32; off; off >>= 1) v += __shfl_xor(v, off, 64);
    return v;
}
__device__ __forceinline__ int waveSumI(int v) {
#pragma unroll
    for (int off = 32; off; off >>= 1) v += __shfl_xor(v, off, 64);
    return v;
}
// quad reduction via DPP quad_perm (VALU-speed; replaces 2 ds_bpermute)
__device__ __forceinline__ float quadSum(float s) {
    int x = __builtin_amdgcn_mov_dpp(__float_as_int(s), 0xB1, 0xf, 0xf, true); // xor1
    s += __int_as_float(x);
    x = __builtin_amdgcn_mov_dpp(__float_as_int(s), 0x4E, 0xf, 0xf, true);     // xor2
    s += __int_as_float(x);
    return s;
}
__device__ __forceinline__ float waveMaxFast(float v) {
    int x = __builtin_amdgcn_mov_dpp(__float_as_int(v), 0xB1, 0xf, 0xf, true);
    v = fmaxf(v, __int_as_float(x));
    x = __builtin_amdgcn_mov_dpp(__float_as_int(v), 0x4E, 0xf, 0xf, true);
    v = fmaxf(v, __int_as_float(x));
#pragma unroll
    for (int off = 4; off <= 32; off <<= 1) v = fmaxf(v, __shfl_xor(v, off, 64));
    return v;
}

// ---- DPP primitives (all-VALU, no DS pipe) ----
template<int C> __device__ __forceinline__ float dppMax(float v) {
    int x = __builtin_amdgcn_mov_dpp(__float_as_int(v), C, 0xf, 0xf, true);
    return fmaxf(v, __int_as_float(x));
}
// wave max; result valid in lanes 32..63 (write from lane 63). All-DPP.
__device__ __forceinline__ float waveMaxTo63(float v) {
    v = dppMax<0xB1>(v);
    v = dppMax<0x4E>(v);
    v = dppMax<0x124>(v);
    v = dppMax<0x128>(v);   // each 16-row now holds row-max replicated
    v = dppMax<0x142>(v);   // row_bcast15
    v = dppMax<0x143>(v);   // row_bcast31 -> lanes 32..63 = full max
    return v;
}

// lgkm-only barrier: LDS visibility without draining global prefetch (vmcnt).
__device__ __forceinline__ void lds_barrier() {
    asm volatile("s_waitcnt lgkmcnt(0)\n\ts_barrier" ::: "memory");
}

#define PKFMA(ep, wp, acc) acc = __builtin_elementwise_fma(ep, wp, acc)

#define MATVEC_QUARTER(Wa, Wb, ev, sOut) {                          \
    const float4 e0 = ev[0], e1 = ev[1], e2 = ev[2], e3 = ev[3];    \
    const float4 e4 = ev[4], e5 = ev[5], e6 = ev[6], e7 = ev[7];    \
    f32x2 a0 = {0.f,0.f}, a1 = {0.f,0.f}, a2 = {0.f,0.f}, a3 = {0.f,0.f}; \
    PKFMA(((f32x2){e0.x, e0.y}), ((f32x2){Wa[0],  Wa[1]}),  a0);    \
    PKFMA(((f32x2){e0.z, e0.w}), ((f32x2){Wa[2],  Wa[3]}),  a1);    \
    PKFMA(((f32x2){e1.x, e1.y}), ((f32x2){Wa[4],  Wa[5]}),  a2);    \
    PKFMA(((f32x2){e1.z, e1.w}), ((f32x2){Wa[6],  Wa[7]}),  a3);    \
    PKFMA(((f32x2){e2.x, e2.y}), ((f32x2){Wa[8],  Wa[9]}),  a0);    \
    PKFMA(((f32x2){e2.z, e2.w}), ((f32x2){Wa[10], Wa[11]}), a1);    \
    PKFMA(((f32x2){e3.x, e3.y}), ((f32x2){Wa[12], Wa[13]}), a2);    \
    PKFMA(((f32x2){e3.z, e3.w}), ((f32x2){Wa[14], Wa[15]}), a3);    \
    PKFMA(((f32x2){e4.x, e4.y}), ((f32x2){Wb[0],  Wb[1]}),  a0);    \
    PKFMA(((f32x2){e4.z, e4.w}), ((f32x2){Wb[2],  Wb[3]}),  a1);    \
    PKFMA(((f32x2){e5.x, e5.y}), ((f32x2){Wb[4],  Wb[5]}),  a2);    \
    PKFMA(((f32x2){e5.z, e5.w}), ((f32x2){Wb[6],  Wb[7]}),  a3);    \
    PKFMA(((f32x2){e6.x, e6.y}), ((f32x2){Wb[8],  Wb[9]}),  a0);    \
    PKFMA(((f32x2){e6.z, e6.w}), ((f32x2){Wb[10], Wb[11]}), a1);    \
    PKFMA(((f32x2){e7.x, e7.y}), ((f32x2){Wb[12], Wb[13]}), a2);    \
    PKFMA(((f32x2){e7.z, e7.w}), ((f32x2){Wb[14], Wb[15]}), a3);    \
    const f32x2 s2 = (a0 + a1) + (a2 + a3);                         \
    sOut = s2[0] + s2[1]; }

// Forward/backward meet-in-the-middle. R2-R4 post-mortem: the compiler refuses
// to keep the per-thread W operand in VGPRs (VGPR_Count pinned at 84 across
// array / waves_per_eu / named-scalar forms) and re-streams ~64 KB/step/CU
// from scratch -- the invariant ~2000-2400 cyc/step floor of EVERY round.
// THIS round: W lives in LDS (67.6 KB dynamic), where placement is under our
// control and nothing is left to spill. Layout Wlds[k*132 + i] (pad 132):
// lane k's b128 chunk c sits on bank-quad (k+c)%8 -> all 8 quads covered,
// structural-floor reads, no swizzle needed. e reads stay uniform-broadcast.
extern "C" __global__ __launch_bounds__(128, 1)
void crf_fb_kernel(const float* __restrict__ em,
                   const int* __restrict__ mask,
                   const int* __restrict__ tgt,
                   const float* __restrict__ trans,
                   const float* __restrict__ start,
                   const int* __restrict__ forb,
                   float* __restrict__ ef,      // [128][KK] forward exp-alpha
                   float* __restrict__ db,      // [128][KK] backward exp-beta
                   float* __restrict__ Mfb)     // [256] scales: fwd 0..127, bwd 128..255
{
    const int tid  = threadIdx.x;       // 0..127 == output state k
    const int k    = tid;
    const int w    = tid >> 6;
    const int lane = tid & 63;
    const bool fwdDir = (blockIdx.x < 2 * BB);
    const int c    = blockIdx.x & (2 * BB - 1);
    const int b    = c & (BB - 1);
    const bool sup = (c < BB);

    extern __shared__ __align__(16) float Wlds[];   // [KK * WSTRIDE] = 67.6 KB
    __shared__ __align__(16) float eLDS[2][KK];
    __shared__ __align__(8)  float wmLDS[2];
    __shared__ float redLDS[2];
    __shared__ int lenLDS;

    // ---- length ----
    if (tid == 0) lenLDS = 0;
    int ps = 0;
    const int4* __restrict__ mrow = (const int4*)(mask + (size_t)b * TT);
#pragma unroll
    for (int it = 0; it < 4; ++it) {
        const int4 m4 = mrow[tid + 128 * it];
        ps += m4.x + m4.y + m4.z + m4.w;
    }
    ps = waveSumI(ps);
    __syncthreads();                     // lenLDS zeroed before adds
    if (lane == 0) atomicAdd(&lenLDS, ps);

    const float st = start[k];
    const float* __restrict__ emrow = em + (size_t)b * TT * KK;
    const int* __restrict__ trow = tgt + (size_t)b * TT * KK;

    // ---- W into LDS, cooperative & coalesced on the global side ----
    // iterate source rows r: lane reads trans[r][tid] (coalesced 512B).
    // value exp(trans[r][tid]) belongs to: fwd  -> Wlds[row=tid][i=r]
    //                                      bwd  -> Wlds[row=r  ][i=tid]
#pragma unroll 4
    for (int r = 0; r < KK; ++r) {
        const float tv = trans[r * KK + tid];
        const int   fv = forb [r * KK + tid];
        const float wv = fv ? 0.0f : __expf(tv);
        const int   R  = fwdDir ? tid : r;
        const int   i  = fwdDir ? r   : tid;
        Wlds[R * WSTRIDE + i] = wv;
    }
    __syncthreads();                     // lenLDS + Wlds ready
    const int len = lenLDS;              // uniform, in [1024, 2048]
    const int mid = len >> 1;
    const int N   = fwdDir ? mid : (len - 1 - mid);   // serial steps (>=511)
    const int t0  = fwdDir ? 0 : (len - 1);

    // ---- init vector at t0: exact max renorm ----
    float v0 = emrow[(size_t)t0 * KK + k];
    if (sup && !trow[(size_t)t0 * KK + k]) v0 = -100000.0f;
    v0 += st;
    const float wm0 = waveMax(v0);
    if (lane == 0) redLDS[w] = wm0;
    __syncthreads();
    const float M0 = fmaxf(redLDS[0], redLDS[1]);
    double M = (double)M0;
    float eNew = __expf(v0 - M0);
    eLDS[0][k] = eNew;

    // iter n consumes bi[time]: fwd time=n; bwd time=len-1-n except the final
    // bwd iter which must NOT apply bi_mid (forward already owns it) -> bi:=0.
    auto loadBi = [&](int n) -> float {
        if (n > N || (!fwdDir && n == N)) return 0.0f;
        const int t = fwdDir ? n : (len - 1 - n);
        float e0 = emrow[(size_t)t * KK + k];
        if (sup) { if (!trow[(size_t)t * KK + k]) e0 = -100000.0f; }
        return e0 + st;
    };

    float biA = loadBi(1), biB = loadBi(2), biC = loadBi(3), biD = loadBi(4);
    const float* __restrict__ Wrow = &Wlds[k * WSTRIDE];
    lds_barrier();                       // publish eLDS[0]

#pragma unroll 4
    for (int n = 1; n <= N; ++n) {
        const int p = (n - 1) & 1;
        const float biN = loadBi(n + 4); // rides across lgkm-only barriers

        // block-renorm (proven cadence): measure at n%4==3 from the previous
        // step's eNew (scalar per lane -> wave DPP-max), apply at n%4==0.
        if ((n & 3) == 3) {
            const float u = waveMaxTo63(__logf(eNew));
            if (lane == 63) wmLDS[w] = u;
        }
        float r = 0.0f;
        if ((n & 3) == 0) {
            const float2 wmv = *(const float2*)wmLDS;  // uniform b64 broadcast
            r = fmaxf(wmv.x, wmv.y);
            M += (double)r;
        }
        const float f = __expf(biA - r);  // off critical path (needed after matvec)

        // full 128-input dot product per lane: W from LDS (per-lane row,
        // bank-quad-spread b128 reads), e via uniform broadcast b128 reads.
        const float4* __restrict__ ev = (const float4*)eLDS[p];
        const float4* __restrict__ wv4 = (const float4*)Wrow;
        f32x2 a0 = {0.f,0.f}, a1 = {0.f,0.f}, a2 = {0.f,0.f}, a3 = {0.f,0.f};
#pragma unroll
        for (int j = 0; j < 32; j += 4) {
            const float4 W0 = wv4[j], W1 = wv4[j + 1], W2 = wv4[j + 2], W3 = wv4[j + 3];
            const float4 E0 = ev[j], E1 = ev[j + 1], E2 = ev[j + 2], E3 = ev[j + 3];
            PKFMA(((f32x2){E0.x, E0.y}), ((f32x2){W0.x, W0.y}), a0);
            PKFMA(((f32x2){E0.z, E0.w}), ((f32x2){W0.z, W0.w}), a1);
            PKFMA(((f32x2){E1.x, E1.y}), ((f32x2){W1.x, W1.y}), a2);
            PKFMA(((f32x2){E1.z, E1.w}), ((f32x2){W1.z, W1.w}), a3);
            PKFMA(((f32x2){E2.x, E2.y}), ((f32x2){W2.x, W2.y}), a0);
            PKFMA(((f32x2){E2.z, E2.w}), ((f32x2){W2.z, W2.w}), a1);
            PKFMA(((f32x2){E3.x, E3.y}), ((f32x2){W3.x, W3.y}), a2);
            PKFMA(((f32x2){E3.z, E3.w}), ((f32x2){W3.z, W3.w}), a3);
        }
        const f32x2 aa = (a0 + a1) + (a2 + a3);
        const float s = aa[0] + aa[1];

        eNew = s * f;
        eLDS[p ^ 1][k] = eNew;           // 1 ds_write_b32, conflict-free

        biA = biB; biB = biC; biC = biD; biD = biN;
        lds_barrier();                   // single barrier/step, only 2 waves
    }

    (fwdDir ? ef : db)[(size_t)c * KK + k] = eNew;
    if (tid == 0) Mfb[(fwdDir ? 0 : 2 * BB) + c] = (float)M;
}

// z[c] = Mf[c] + Mb[c] + log(dot(ef[c], db[c])); out[b] = z[b] - z[b+64]
extern "C" __global__ void crf_combine_kernel(const float* __restrict__ ef,
                                              const float* __restrict__ db,
                                              const float* __restrict__ Mfb,
                                              float* __restrict__ out)
{
    const int b = blockIdx.x;
    const int tid = threadIdx.x;         // 0..127 = state
    const int wv = tid >> 6, lane = tid & 63;
    __shared__ float red[2][2];
    __shared__ float z[2];
#pragma unroll
    for (int s = 0; s < 2; ++s) {
        const int c = b + s * BB;
        const float v = ef[(size_t)c * KK + tid] * db[(size_t)c * KK + tid];
        const float p = waveSum(v);
        if (lane == 0) red[s][wv] = p;
    }
    __syncthreads();
    if (tid < 2) {
        const int c = b + tid * BB;
        z[tid] = Mfb[c] + Mfb[2 * BB + c] + __logf(red[tid][0] + red[tid][1]);
    }
    __syncthreads();
    if (tid == 0) out[b] = z[0] - z[1];
}

// ---------------- fallback (R8, proven): used only if ws is too small -------
extern "C" __global__ __launch_bounds__(512)
__attribute__((amdgpu_waves_per_eu(2, 2)))
void crf_chain_kernel(const float* __restrict__ em, const int* __restrict__ mask,
                      const int* __restrict__ tgt, const float* __restrict__ trans,
                      const float* __restrict__ start, const int* __restrict__ forb,
                      float* __restrict__ zbuf)
{
    const int tid = threadIdx.x;
    const int k = tid >> 2, q = tid & 3, w = tid >> 6, lane = tid & 63;
    const int c = blockIdx.x, b = c & (BB - 1);
    const bool sup = (c < BB);
    __shared__ __align__(16) float eLDS[2][KK];
    __shared__ float wmLDS[8];
    __shared__ float redLDS[8];
    __shared__ int lenLDS;
    if (tid == 0) lenLDS = 0;
    const int4 m4 = ((const int4*)(mask + (size_t)b * TT))[tid];
    int ps = m4.x + m4.y + m4.z + m4.w;
    ps = waveSumI(ps);
    __syncthreads();
    if (lane == 0) atomicAdd(&lenLDS, ps);
    const float st = start[k];
    const float* __restrict__ emrow = em + (size_t)b * TT * KK;
    const int* __restrict__ trow = tgt + (size_t)b * TT * KK;
    const int ib = q * 32;
    f32x16 Wa, Wb;
#pragma unroll
    for (int j = 0; j < 16; ++j) {
        Wa[j] = forb[(ib + j     ) * KK + k] ? 0.0f : __expf(trans[(ib + j     ) * KK + k]);
        Wb[j] = forb[(ib + 16 + j) * KK + k] ? 0.0f : __expf(trans[(ib + 16 + j) * KK + k]);
    }
    float v0 = emrow[k];
    if (sup && !trow[k]) v0 = -100000.0f;
    v0 += st;
    const float wm0 = waveMax(v0);
    if (lane == 0) redLDS[w] = wm0;
    __syncthreads();
    const int len = lenLDS;
    float M0 = fmaxf(fmaxf(fmaxf(redLDS[0], redLDS[1]), fmaxf(redLDS[2], redLDS[3])),
                     fmaxf(fmaxf(redLDS[4], redLDS[5]), fmaxf(redLDS[6], redLDS[7])));
    double M = (double)M0;
    float eNew = __expf(v0 - M0);
    if (q == 0) eLDS[0][k] = eNew;
    auto bival = [&](int t) -> float {
        float e0 = emrow[(size_t)t * KK + k];
        if (sup) { if (!trow[(size_t)t * KK + k]) e0 = -100000.0f; }
        return e0 + st;
    };
    float biA = (len > 1) ? bival(1) : 0.0f;
    float biB = (len > 2) ? bival(2) : 0.0f;
    float biC = (len > 3) ? bival(3) : 0.0f;
    float biD = (len > 4) ? bival(4) : 0.0f;
    float sPrev = 1.0f, baPrev = 0.0f;
    lds_barrier();
#pragma unroll 4
    for (int t = 1; t < len; ++t) {
        const int p = (t - 1) & 1;
        const float biN = (t + 4 < len) ? bival(t + 4) : 0.0f;
        if ((t & 3) == 3) {
            const float u = __logf(sPrev) + baPrev;
            const float wmx = waveMaxFast(u);
            if (lane == 0) wmLDS[w] = wmx;
        }
        float r = 0.0f;
        if ((t & 3) == 0) {
            r = fmaxf(fmaxf(fmaxf(wmLDS[0], wmLDS[1]), fmaxf(wmLDS[2], wmLDS[3])),
                      fmaxf(fmaxf(wmLDS[4], wmLDS[5]), fmaxf(wmLDS[6], wmLDS[7])));
            M += (double)r;
        }
        const float ba = biA - r;
        const float f = __expf(ba);
        const float4* __restrict__ ev = (const float4*)eLDS[p] + q * 8;
        float s;
        MATVEC_QUARTER(Wa, Wb, ev, s)
        s = quadSum(s);
        eNew = s * f;
        if (q == 0) eLDS[p ^ 1][k] = eNew;
        sPrev = s; baPrev = ba;
        biA = biB; biB = biC; biC = biD; biD = biN;
        lds_barrier();
    }
    const float sm = waveSum((q == 0) ? eNew : 0.0f);
    if (lane == 0) redLDS[w] = sm;
    __syncthreads();
    if (tid == 0) {
        const float ss = ((redLDS[0] + redLDS[1]) + (redLDS[2] + redLDS[3]))
                       + ((redLDS[4] + redLDS[5]) + (redLDS[6] + redLDS[7]));
        zbuf[c] = (float)(M + (double)__logf(ss));
    }
}

extern "C" __global__ void crf_final_kernel(const float* __restrict__ z,
                                            float* __restrict__ out)
{
    const int b = threadIdx.x;
    out[b] = z[b] - z[b + BB];
}

extern "C" void kernel_launch(void* const* d_in, const int* in_sizes, int n_in,
                              void* d_out, int out_size, void* d_ws, size_t ws_size,
                              hipStream_t stream) {
    const float* em    = (const float*)d_in[0];
    const int*   mask  = (const int*)d_in[1];
    const int*   tgt   = (const int*)d_in[2];
    const float* trans = (const float*)d_in[3];
    const float* start = (const float*)d_in[4];
    const int*   forb  = (const int*)d_in[5];

    const size_t need = (size_t)(2 * 2 * BB * KK + 4 * BB) * sizeof(float); // 132 KB
    if (ws_size >= need) {
        float* ef  = (float*)d_ws;                       // [128][128]
        float* db  = ef + 2 * BB * KK;                   // [128][128]
        float* Mfb = db + 2 * BB * KK;                   // [256]
        const size_t wbytes = (size_t)KK * WSTRIDE * sizeof(float); // 67,584 B
        crf_fb_kernel<<<4 * BB, 128, wbytes, stream>>>(em, mask, tgt, trans, start,
                                                       forb, ef, db, Mfb);
        crf_combine_kernel<<<BB, 128, 0, stream>>>(ef, db, Mfb, (float*)d_out);
    } else {
        float* zbuf = (float*)d_ws;
        crf_chain_kernel<<<2 * BB, 512, 0, stream>>>(em, mask, tgt, trans, start,
                                                     forb, zbuf);
        crf_final_kernel<<<1, BB, 0, stream>>>(zbuf, (float*)d_out);
    }
}

// Round 6
// 938.039 us; speedup vs baseline: 1.3144x; 1.3144x over previous
//
#include <hip/hip_runtime.h>
#include <stdint.h>

#define BB 64
#define TT 2048
#define KK 128
#define CH 32         // bi-staging chunk: steps per chunk
#define WSTRIDE 132   // words per W row: pad 128+4 -> lane k / chunk c hits
                      // bank-quad (k+c)%8: all 8 quads, structural-floor reads

typedef float f32x16 __attribute__((ext_vector_type(16)));
typedef float f32x2  __attribute__((ext_vector_type(2)));

__device__ __forceinline__ float waveMax(float v) {
#pragma unroll
    for (int off = 32; off; off >>= 1) v = fmaxf(v, __shfl_xor(v, off, 64));
    return v;
}
__device__ __forceinline__ float waveSum(float v) {
#pragma unroll
    for (int off = 32; off; off >>= 1) v += __shfl_xor(v, off, 64);
    return v;
}
__device__ __forceinline__ int waveSumI(int v) {
#pragma unroll
    for (int off = 32; off; off >>= 1) v += __shfl_xor(v, off, 64);
    return v;
}
// quad reduction via DPP quad_perm (VALU-speed; replaces 2 ds_bpermute)
__device__ __forceinline__ float quadSum(float s) {
    int x = __builtin_amdgcn_mov_dpp(__float_as_int(s), 0xB1, 0xf, 0xf, true); // xor1
    s += __int_as_float(x);
    x = __builtin_amdgcn_mov_dpp(__float_as_int(s), 0x4E, 0xf, 0xf, true);     // xor2
    s += __int_as_float(x);
    return s;
}
__device__ __forceinline__ float waveMaxFast(float v) {
    int x = __builtin_amdgcn_mov_dpp(__float_as_int(v), 0xB1, 0xf, 0xf, true);
    v = fmaxf(v, __int_as_float(x));
    x = __builtin_amdgcn_mov_dpp(__float_as_int(v), 0x4E, 0xf, 0xf, true);
    v = fmaxf(v, __int_as_float(x));
#pragma unroll
    for (int off = 4; off <= 32; off <<= 1) v = fmaxf(v, __shfl_xor(v, off, 64));
    return v;
}

// ---- DPP primitives (all-VALU, no DS pipe) ----
template<int C> __device__ __forceinline__ float dppMax(float v) {
    int x = __builtin_amdgcn_mov_dpp(__float_as_int(v), C, 0xf, 0xf, true);
    return fmaxf(v, __int_as_float(x));
}
// wave max; result valid in lanes 32..63 (write from lane 63). All-DPP.
__device__ __forceinline__ float waveMaxTo63(float v) {
    v = dppMax<0xB1>(v);
    v = dppMax<0x4E>(v);
    v = dppMax<0x124>(v);
    v = dppMax<0x128>(v);   // each 16-row now holds row-max replicated
    v = dppMax<0x142>(v);   // row_bcast15
    v = dppMax<0x143>(v);   // row_bcast31 -> lanes 32..63 = full max
    return v;
}

// lgkm-only barrier: LDS visibility without draining global prefetch (vmcnt).
// NOTE (R6 theory): the "memory" clobber may cause the waitcnt pass to insert
// s_waitcnt vmcnt(0) before this asm anyway. This round makes the steady-state
// loop globally-quiet so that even a forced vmcnt(0) costs zero.
__device__ __forceinline__ void lds_barrier() {
    asm volatile("s_waitcnt lgkmcnt(0)\n\ts_barrier" ::: "memory");
}

#define PKFMA(ep, wp, acc) acc = __builtin_elementwise_fma(ep, wp, acc)

#define MATVEC_QUARTER(Wa, Wb, ev, sOut) {                          \
    const float4 e0 = ev[0], e1 = ev[1], e2 = ev[2], e3 = ev[3];    \
    const float4 e4 = ev[4], e5 = ev[5], e6 = ev[6], e7 = ev[7];    \
    f32x2 a0 = {0.f,0.f}, a1 = {0.f,0.f}, a2 = {0.f,0.f}, a3 = {0.f,0.f}; \
    PKFMA(((f32x2){e0.x, e0.y}), ((f32x2){Wa[0],  Wa[1]}),  a0);    \
    PKFMA(((f32x2){e0.z, e0.w}), ((f32x2){Wa[2],  Wa[3]}),  a1);    \
    PKFMA(((f32x2){e1.x, e1.y}), ((f32x2){Wa[4],  Wa[5]}),  a2);    \
    PKFMA(((f32x2){e1.z, e1.w}), ((f32x2){Wa[6],  Wa[7]}),  a3);    \
    PKFMA(((f32x2){e2.x, e2.y}), ((f32x2){Wa[8],  Wa[9]}),  a0);    \
    PKFMA(((f32x2){e2.z, e2.w}), ((f32x2){Wa[10], Wa[11]}), a1);    \
    PKFMA(((f32x2){e3.x, e3.y}), ((f32x2){Wa[12], Wa[13]}), a2);    \
    PKFMA(((f32x2){e3.z, e3.w}), ((f32x2){Wa[14], Wa[15]}), a3);    \
    PKFMA(((f32x2){e4.x, e4.y}), ((f32x2){Wb[0],  Wb[1]}),  a0);    \
    PKFMA(((f32x2){e4.z, e4.w}), ((f32x2){Wb[2],  Wb[3]}),  a1);    \
    PKFMA(((f32x2){e5.x, e5.y}), ((f32x2){Wb[4],  Wb[5]}),  a2);    \
    PKFMA(((f32x2){e5.z, e5.w}), ((f32x2){Wb[6],  Wb[7]}),  a3);    \
    PKFMA(((f32x2){e6.x, e6.y}), ((f32x2){Wb[8],  Wb[9]}),  a0);    \
    PKFMA(((f32x2){e6.z, e6.w}), ((f32x2){Wb[10], Wb[11]}), a1);    \
    PKFMA(((f32x2){e7.x, e7.y}), ((f32x2){Wb[12], Wb[13]}), a2);    \
    PKFMA(((f32x2){e7.z, e7.w}), ((f32x2){Wb[14], Wb[15]}), a3);    \
    const f32x2 s2 = (a0 + a1) + (a2 + a3);                         \
    sOut = s2[0] + s2[1]; }

// Forward/backward meet-in-the-middle. R5 post-mortem: scratch theory DEAD
// (W in LDS, VGPR=28, zero spill -> same ~2690 cyc/step floor). The one thing
// every round shared: a PER-STEP GLOBAL LOAD riding across the barrier. If the
// compiler drains vmcnt(0) at the memory-clobbered barrier asm, each step pays
// full HBM/L2 latency. THIS round: bi is staged in 32-step chunks into a
// double-buffered biLDS (composed: mask+start applied at stage time); the
// steady-state loop does ZERO global memory ops -> vmcnt is 0 at every inner
// barrier no matter what the compiler inserts. Chunk stall amortizes ~30cyc/step.
extern "C" __global__ __launch_bounds__(128, 1)
void crf_fb_kernel(const float* __restrict__ em,
                   const int* __restrict__ mask,
                   const int* __restrict__ tgt,
                   const float* __restrict__ trans,
                   const float* __restrict__ start,
                   const int* __restrict__ forb,
                   float* __restrict__ ef,      // [128][KK] forward exp-alpha
                   float* __restrict__ db,      // [128][KK] backward exp-beta
                   float* __restrict__ Mfb)     // [256] scales: fwd 0..127, bwd 128..255
{
    const int tid  = threadIdx.x;       // 0..127 == output state k
    const int k    = tid;
    const int w    = tid >> 6;
    const int lane = tid & 63;
    const bool fwdDir = (blockIdx.x < 2 * BB);
    const int c    = blockIdx.x & (2 * BB - 1);
    const int b    = c & (BB - 1);
    const bool sup = (c < BB);

    extern __shared__ __align__(16) float Wlds[];   // [KK * WSTRIDE] = 67.6 KB
    __shared__ __align__(16) float biLDS[2][CH][KK]; // 32 KB composed bi chunks
    __shared__ __align__(16) float eLDS[2][KK];
    __shared__ __align__(8)  float wmLDS[2];
    __shared__ float redLDS[2];
    __shared__ int lenLDS;

    // ---- length ----
    if (tid == 0) lenLDS = 0;
    int ps = 0;
    const int4* __restrict__ mrow = (const int4*)(mask + (size_t)b * TT);
#pragma unroll
    for (int it = 0; it < 4; ++it) {
        const int4 m4 = mrow[tid + 128 * it];
        ps += m4.x + m4.y + m4.z + m4.w;
    }
    ps = waveSumI(ps);
    __syncthreads();                     // lenLDS zeroed before adds
    if (lane == 0) atomicAdd(&lenLDS, ps);

    const float st = start[k];
    const float* __restrict__ emrow = em + (size_t)b * TT * KK;
    const int* __restrict__ trow = tgt + (size_t)b * TT * KK;

    // ---- W into LDS, cooperative & coalesced on the global side ----
    // iterate source rows r: lane reads trans[r][tid] (coalesced 512B).
    // value exp(trans[r][tid]) belongs to: fwd  -> Wlds[row=tid][i=r]
    //                                      bwd  -> Wlds[row=r  ][i=tid]
#pragma unroll 4
    for (int r = 0; r < KK; ++r) {
        const float tv = trans[r * KK + tid];
        const int   fv = forb [r * KK + tid];
        const float wv = fv ? 0.0f : __expf(tv);
        const int   R  = fwdDir ? tid : r;
        const int   i  = fwdDir ? r   : tid;
        Wlds[R * WSTRIDE + i] = wv;
    }
    __syncthreads();                     // lenLDS + Wlds ready
    const int len = lenLDS;              // uniform, in [1024, 2048]
    const int mid = len >> 1;
    const int N   = fwdDir ? mid : (len - 1 - mid);   // serial steps (>=511)
    const int t0  = fwdDir ? 0 : (len - 1);

    // ---- init vector at t0: exact max renorm ----
    float v0 = emrow[(size_t)t0 * KK + k];
    if (sup && !trow[(size_t)t0 * KK + k]) v0 = -100000.0f;
    v0 += st;
    const float wm0 = waveMax(v0);
    if (lane == 0) redLDS[w] = wm0;
    __syncthreads();
    const float M0 = fmaxf(redLDS[0], redLDS[1]);
    double M = (double)M0;
    float eNew = __expf(v0 - M0);
    eLDS[0][k] = eNew;

    // ---- chunked bi staging: compose mask+start at stage time ----
    // chunk m covers n in [1+CH*m, CH+CH*m]; row pos in biLDS:
    //   fwd: t = base_n + pos          (t_base = base_n)
    //   bwd: t = t_base + pos, t_base = len - base_n - CH, pos = CH-1-i
    // Each thread stages 8 float4s: row = (tid>>5) + 4*i, col = (tid&31)*4
    // -> per row, 32 consecutive threads cover 512B (coalesced).
    const int scol = (tid & 31) << 2;
    const float4 stc = *(const float4*)(start + scol);
    auto stageChunk = [&](int bf, int m) {
        const int base_n = 1 + CH * m;
        const int t_base = fwdDir ? base_n : (len - base_n - CH);
#pragma unroll
        for (int i = 0; i < 8; ++i) {
            const int row = (tid >> 5) + (i << 2);
            const int t = t_base + row;
            float4 e4 = *(const float4*)(emrow + (size_t)t * KK + scol);
            if (sup) {
                const int4 t4 = *(const int4*)(trow + (size_t)t * KK + scol);
                e4.x = t4.x ? e4.x : -100000.0f;
                e4.y = t4.y ? e4.y : -100000.0f;
                e4.z = t4.z ? e4.z : -100000.0f;
                e4.w = t4.w ? e4.w : -100000.0f;
            }
            e4.x += stc.x; e4.y += stc.y; e4.z += stc.z; e4.w += stc.w;
            *(float4*)&biLDS[bf][row][scol] = e4;
        }
    };

    const int nChunks = (N + CH - 1) / CH;
    int buf = 0;
    stageChunk(0, 0);
    const float* __restrict__ Wrow = &Wlds[k * WSTRIDE];
    lds_barrier();                       // publish eLDS[0] + biLDS[0]

    for (int m = 0; m < nChunks; ++m) {
        if (m + 1 < nChunks) stageChunk(buf ^ 1, m + 1);
        const int base_n = 1 + CH * m;
        const int rem = N - base_n + 1;
        const int lim = rem < CH ? rem : CH;
#pragma unroll 4
        for (int i = 0; i < lim; ++i) {
            const int n = base_n + i;
            const int p = (n - 1) & 1;

            // bi from LDS (2-way bank aliasing: free). bwd final step: bi=0
            // (forward already owns bi_mid).
            const int pos = fwdDir ? i : (CH - 1 - i);
            float bi = biLDS[buf][pos][k];
            if (!fwdDir && n == N) bi = 0.0f;

            // block-renorm (proven cadence): measure at n%4==3 from previous
            // step's eNew (scalar per lane -> wave DPP-max), apply at n%4==0.
            if ((n & 3) == 3) {
                const float u = waveMaxTo63(__logf(eNew));
                if (lane == 63) wmLDS[w] = u;
            }
            float r = 0.0f;
            if ((n & 3) == 0) {
                const float2 wmv = *(const float2*)wmLDS;  // uniform b64 bcast
                r = fmaxf(wmv.x, wmv.y);
                M += (double)r;
            }
            const float f = __expf(bi - r);  // overlaps matvec

            // full 128-input dot product per lane: W from LDS (per-lane row,
            // bank-quad-spread b128), e via uniform broadcast b128 reads.
            const float4* __restrict__ ev = (const float4*)eLDS[p];
            const float4* __restrict__ wv4 = (const float4*)Wrow;
            f32x2 a0 = {0.f,0.f}, a1 = {0.f,0.f}, a2 = {0.f,0.f}, a3 = {0.f,0.f};
#pragma unroll
            for (int j = 0; j < 32; j += 4) {
                const float4 W0 = wv4[j], W1 = wv4[j + 1], W2 = wv4[j + 2], W3 = wv4[j + 3];
                const float4 E0 = ev[j], E1 = ev[j + 1], E2 = ev[j + 2], E3 = ev[j + 3];
                PKFMA(((f32x2){E0.x, E0.y}), ((f32x2){W0.x, W0.y}), a0);
                PKFMA(((f32x2){E0.z, E0.w}), ((f32x2){W0.z, W0.w}), a1);
                PKFMA(((f32x2){E1.x, E1.y}), ((f32x2){W1.x, W1.y}), a2);
                PKFMA(((f32x2){E1.z, E1.w}), ((f32x2){W1.z, W1.w}), a3);
                PKFMA(((f32x2){E2.x, E2.y}), ((f32x2){W2.x, W2.y}), a0);
                PKFMA(((f32x2){E2.z, E2.w}), ((f32x2){W2.z, W2.w}), a1);
                PKFMA(((f32x2){E3.x, E3.y}), ((f32x2){W3.x, W3.y}), a2);
                PKFMA(((f32x2){E3.z, E3.w}), ((f32x2){W3.z, W3.w}), a3);
            }
            const f32x2 aa = (a0 + a1) + (a2 + a3);
            const float s = aa[0] + aa[1];

            eNew = s * f;
            eLDS[p ^ 1][k] = eNew;           // 1 ds_write_b32, conflict-free

            lds_barrier();                   // globally-quiet: vmcnt==0 here
        }
        buf ^= 1;
    }

    (fwdDir ? ef : db)[(size_t)c * KK + k] = eNew;
    if (tid == 0) Mfb[(fwdDir ? 0 : 2 * BB) + c] = (float)M;
}

// z[c] = Mf[c] + Mb[c] + log(dot(ef[c], db[c])); out[b] = z[b] - z[b+64]
extern "C" __global__ void crf_combine_kernel(const float* __restrict__ ef,
                                              const float* __restrict__ db,
                                              const float* __restrict__ Mfb,
                                              float* __restrict__ out)
{
    const int b = blockIdx.x;
    const int tid = threadIdx.x;         // 0..127 = state
    const int wv = tid >> 6, lane = tid & 63;
    __shared__ float red[2][2];
    __shared__ float z[2];
#pragma unroll
    for (int s = 0; s < 2; ++s) {
        const int c = b + s * BB;
        const float v = ef[(size_t)c * KK + tid] * db[(size_t)c * KK + tid];
        const float p = waveSum(v);
        if (lane == 0) red[s][wv] = p;
    }
    __syncthreads();
    if (tid < 2) {
        const int c = b + tid * BB;
        z[tid] = Mfb[c] + Mfb[2 * BB + c] + __logf(red[tid][0] + red[tid][1]);
    }
    __syncthreads();
    if (tid == 0) out[b] = z[0] - z[1];
}

// ---------------- fallback (R8, proven): used only if ws is too small -------
extern "C" __global__ __launch_bounds__(512)
__attribute__((amdgpu_waves_per_eu(2, 2)))
void crf_chain_kernel(const float* __restrict__ em, const int* __restrict__ mask,
                      const int* __restrict__ tgt, const float* __restrict__ trans,
                      const float* __restrict__ start, const int* __restrict__ forb,
                      float* __restrict__ zbuf)
{
    const int tid = threadIdx.x;
    const int k = tid >> 2, q = tid & 3, w = tid >> 6, lane = tid & 63;
    const int c = blockIdx.x, b = c & (BB - 1);
    const bool sup = (c < BB);
    __shared__ __align__(16) float eLDS[2][KK];
    __shared__ float wmLDS[8];
    __shared__ float redLDS[8];
    __shared__ int lenLDS;
    if (tid == 0) lenLDS = 0;
    const int4 m4 = ((const int4*)(mask + (size_t)b * TT))[tid];
    int ps = m4.x + m4.y + m4.z + m4.w;
    ps = waveSumI(ps);
    __syncthreads();
    if (lane == 0) atomicAdd(&lenLDS, ps);
    const float st = start[k];
    const float* __restrict__ emrow = em + (size_t)b * TT * KK;
    const int* __restrict__ trow = tgt + (size_t)b * TT * KK;
    const int ib = q * 32;
    f32x16 Wa, Wb;
#pragma unroll
    for (int j = 0; j < 16; ++j) {
        Wa[j] = forb[(ib + j     ) * KK + k] ? 0.0f : __expf(trans[(ib + j     ) * KK + k]);
        Wb[j] = forb[(ib + 16 + j) * KK + k] ? 0.0f : __expf(trans[(ib + 16 + j) * KK + k]);
    }
    float v0 = emrow[k];
    if (sup && !trow[k]) v0 = -100000.0f;
    v0 += st;
    const float wm0 = waveMax(v0);
    if (lane == 0) redLDS[w] = wm0;
    __syncthreads();
    const int len = lenLDS;
    float M0 = fmaxf(fmaxf(fmaxf(redLDS[0], redLDS[1]), fmaxf(redLDS[2], redLDS[3])),
                     fmaxf(fmaxf(redLDS[4], redLDS[5]), fmaxf(redLDS[6], redLDS[7])));
    double M = (double)M0;
    float eNew = __expf(v0 - M0);
    if (q == 0) eLDS[0][k] = eNew;
    auto bival = [&](int t) -> float {
        float e0 = emrow[(size_t)t * KK + k];
        if (sup) { if (!trow[(size_t)t * KK + k]) e0 = -100000.0f; }
        return e0 + st;
    };
    float biA = (len > 1) ? bival(1) : 0.0f;
    float biB = (len > 2) ? bival(2) : 0.0f;
    float biC = (len > 3) ? bival(3) : 0.0f;
    float biD = (len > 4) ? bival(4) : 0.0f;
    float sPrev = 1.0f, baPrev = 0.0f;
    lds_barrier();
#pragma unroll 4
    for (int t = 1; t < len; ++t) {
        const int p = (t - 1) & 1;
        const float biN = (t + 4 < len) ? bival(t + 4) : 0.0f;
        if ((t & 3) == 3) {
            const float u = __logf(sPrev) + baPrev;
            const float wmx = waveMaxFast(u);
            if (lane == 0) wmLDS[w] = wmx;
        }
        float r = 0.0f;
        if ((t & 3) == 0) {
            r = fmaxf(fmaxf(fmaxf(wmLDS[0], wmLDS[1]), fmaxf(wmLDS[2], wmLDS[3])),
                      fmaxf(fmaxf(wmLDS[4], wmLDS[5]), fmaxf(wmLDS[6], wmLDS[7])));
            M += (double)r;
        }
        const float ba = biA - r;
        const float f = __expf(ba);
        const float4* __restrict__ ev = (const float4*)eLDS[p] + q * 8;
        float s;
        MATVEC_QUARTER(Wa, Wb, ev, s)
        s = quadSum(s);
        eNew = s * f;
        if (q == 0) eLDS[p ^ 1][k] = eNew;
        sPrev = s; baPrev = ba;
        biA = biB; biB = biC; biC = biD; biD = biN;
        lds_barrier();
    }
    const float sm = waveSum((q == 0) ? eNew : 0.0f);
    if (lane == 0) redLDS[w] = sm;
    __syncthreads();
    if (tid == 0) {
        const float ss = ((redLDS[0] + redLDS[1]) + (redLDS[2] + redLDS[3]))
                       + ((redLDS[4] + redLDS[5]) + (redLDS[6] + redLDS[7]));
        zbuf[c] = (float)(M + (double)__logf(ss));
    }
}

extern "C" __global__ void crf_final_kernel(const float* __restrict__ z,
                                            float* __restrict__ out)
{
    const int b = threadIdx.x;
    out[b] = z[b] - z[b + BB];
}

extern "C" void kernel_launch(void* const* d_in, const int* in_sizes, int n_in,
                              void* d_out, int out_size, void* d_ws, size_t ws_size,
                              hipStream_t stream) {
    const float* em    = (const float*)d_in[0];
    const int*   mask  = (const int*)d_in[1];
    const int*   tgt   = (const int*)d_in[2];
    const float* trans = (const float*)d_in[3];
    const float* start = (const float*)d_in[4];
    const int*   forb  = (const int*)d_in[5];

    const size_t need = (size_t)(2 * 2 * BB * KK + 4 * BB) * sizeof(float); // 132 KB
    if (ws_size >= need) {
        float* ef  = (float*)d_ws;                       // [128][128]
        float* db  = ef + 2 * BB * KK;                   // [128][128]
        float* Mfb = db + 2 * BB * KK;                   // [256]
        const size_t wbytes = (size_t)KK * WSTRIDE * sizeof(float); // 67,584 B
        crf_fb_kernel<<<4 * BB, 128, wbytes, stream>>>(em, mask, tgt, trans, start,
                                                       forb, ef, db, Mfb);
        crf_combine_kernel<<<BB, 128, 0, stream>>>(ef, db, Mfb, (float*)d_out);
    } else {
        float* zbuf = (float*)d_ws;
        crf_chain_kernel<<<2 * BB, 512, 0, stream>>>(em, mask, tgt, trans, start,
                                                     forb, zbuf);
        crf_final_kernel<<<1, BB, 0, stream>>>(zbuf, (float*)d_out);
    }
}